// Round 9
// baseline (275.890 us; speedup 1.0000x reference)
//
#include <hip/hip_runtime.h>
#include <math.h>

// Native vector type: __builtin_nontemporal_load/store require scalar,
// pointer, or NATIVE vector types (HIP_vector_type float4 is rejected).
typedef float f32x4 __attribute__((ext_vector_type(4)));

// ---------------------------------------------------------------------------
// Kernel A: per-token metadata. One thread per token; 6-step binary search
// over B=32 offsets. Writes combined int2 {pos, bucket}.
// ---------------------------------------------------------------------------
__global__ void hstu_meta_kernel(const int* __restrict__ seq_lengths,
                                 const int* __restrict__ seq_offsets,
                                 const int* __restrict__ num_targets,
                                 const int* __restrict__ seq_timestamps,
                                 int2* __restrict__ meta,
                                 int T, int B, int NPOS, int NTIME) {
    int t = blockIdx.x * blockDim.x + threadIdx.x;
    if (t >= T) return;

    int lo = 0, hi = B;
    while (hi - lo > 1) {
        int mid = (lo + hi) >> 1;
        if (seq_offsets[mid] <= t) lo = mid; else hi = mid;
    }
    const int sid   = lo;
    const int off   = seq_offsets[sid];
    const int L     = seq_lengths[sid];
    const int local = t - off;

    int high = L - num_targets[sid];
    if (high > NPOS - 1) high = NPOS - 1;
    int pos = local < high ? local : high;
    if (pos < 0) pos = 0;
    if (pos > NPOS - 1) pos = NPOS - 1;

    const int qts   = seq_timestamps[off + L - 1];
    int delta = qts - seq_timestamps[t];
    if (delta < 0) delta = 0;
    int bucket = (int)floorf(sqrtf((float)delta));
    if (bucket < 0) bucket = 0;
    if (bucket > NTIME) bucket = NTIME;

    meta[t] = make_int2(pos, bucket);
}

// ---------------------------------------------------------------------------
// Kernel B (hot): wave-per-row, RPW contiguous rows per wave, XCD-swizzled
// blocks. Each XCD owns a contiguous token band -> its pos/ts gather window
// fits its private 4MB L2 (round-robin dispatch would interleave the token
// range across XCDs and thrash all 8 L2s via L3/fabric). Contiguous rows per
// wave also give L1 reuse on ts rows (bucket changes slowly with t).
// emb/out use nontemporal hints so the 268MB stream doesn't evict the tables.
// ---------------------------------------------------------------------------
template <int C4S, int RPW>   // C4S = log2(float4s per row); D=512 -> 7
__global__ void __launch_bounds__(256)
hstu_fuse_rows(const f32x4* __restrict__ emb,
               const f32x4* __restrict__ pos_emb,
               const f32x4* __restrict__ ts_emb,
               const int2* __restrict__ meta,
               f32x4* __restrict__ out,
               int T, float alpha) {
    constexpr int C4   = 1 << C4S;
    constexpr int F4PL = C4 >> 6;    // float4s per lane per row (2 for D=512)
    static_assert(F4PL >= 1, "row must span at least one float4 per lane");

    // XCD swizzle: grid is padded to a multiple of 8, so bid -> (xcd, chunk)
    // is bijective. XCD k gets blocks {k, k+8, ...} under round-robin
    // dispatch; remapping gives it the contiguous chunk [k*cpx, (k+1)*cpx).
    const int cpx = gridDim.x >> 3;                       // blocks per XCD
    const int sw  = (blockIdx.x & 7) * cpx + (blockIdx.x >> 3);

    const int lane = threadIdx.x & 63;
    const int wpb  = blockDim.x >> 6;
    const int w    = sw * wpb + (threadIdx.x >> 6);       // global wave id
    const int t0   = w * RPW;
    if (t0 >= T) return;
    const int tend = (t0 + RPW < T) ? (t0 + RPW) : T;

    int2 m = meta[t0];
    for (int t = t0; t < tend; ++t) {
        const int tn = t + 1;
        int2 mn = m;
        if (tn < tend) mn = meta[tn];    // prefetch next row's indices

        const f32x4* ep = emb     + (((size_t)t)   << C4S) + lane;
        const f32x4* pp = pos_emb + (((size_t)m.x) << C4S) + lane;
        const f32x4* tp = ts_emb  + (((size_t)m.y) << C4S) + lane;

        f32x4 e[F4PL], p[F4PL], q[F4PL];
#pragma unroll
        for (int j = 0; j < F4PL; ++j) e[j] = __builtin_nontemporal_load(ep + 64 * j);
#pragma unroll
        for (int j = 0; j < F4PL; ++j) p[j] = pp[64 * j];
#pragma unroll
        for (int j = 0; j < F4PL; ++j) q[j] = tp[64 * j];

        f32x4* op = out + (((size_t)t) << C4S) + lane;
#pragma unroll
        for (int j = 0; j < F4PL; ++j) {
            f32x4 o;
            o.x = fmaf(e[j].x, alpha, p[j].x + q[j].x);
            o.y = fmaf(e[j].y, alpha, p[j].y + q[j].y);
            o.z = fmaf(e[j].z, alpha, p[j].z + q[j].z);
            o.w = fmaf(e[j].w, alpha, p[j].w + q[j].w);
            __builtin_nontemporal_store(o, op + 64 * j);
        }

        m = mn;
    }
}

// ---------------------------------------------------------------------------
// Generic fallback (D/4 not a multiple of 64): per-float4 mapping.
// ---------------------------------------------------------------------------
__global__ void __launch_bounds__(256)
hstu_fuse_kernel_gen(const f32x4* __restrict__ emb,
                     const f32x4* __restrict__ pos_emb,
                     const f32x4* __restrict__ ts_emb,
                     const int2* __restrict__ meta,
                     f32x4* __restrict__ out,
                     int total4, int c4, float alpha) {
    const int stride = gridDim.x * blockDim.x;
    for (int idx = blockIdx.x * blockDim.x + threadIdx.x; idx < total4; idx += stride) {
        const int t = idx / c4;
        const int c = idx - t * c4;
        const int2 m = meta[t];
        const f32x4 e  = emb[idx];
        const f32x4 pe = pos_emb[(size_t)m.x * c4 + c];
        const f32x4 te = ts_emb[(size_t)m.y * c4 + c];
        f32x4 o;
        o.x = fmaf(e.x, alpha, pe.x + te.x);
        o.y = fmaf(e.y, alpha, pe.y + te.y);
        o.z = fmaf(e.z, alpha, pe.z + te.z);
        o.w = fmaf(e.w, alpha, pe.w + te.w);
        out[idx] = o;
    }
}

extern "C" void kernel_launch(void* const* d_in, const int* in_sizes, int n_in,
                              void* d_out, int out_size, void* d_ws, size_t ws_size,
                              hipStream_t stream) {
    // Input order: max_seq_len, seq_lengths, seq_offsets, seq_embeddings,
    //              num_targets, seq_timestamps, pos_emb, ts_emb
    const int* seq_lengths    = (const int*)d_in[1];
    const int* seq_offsets    = (const int*)d_in[2];
    const float* seq_emb      = (const float*)d_in[3];
    const int* num_targets    = (const int*)d_in[4];
    const int* seq_timestamps = (const int*)d_in[5];
    const float* pos_emb      = (const float*)d_in[6];
    const float* ts_emb       = (const float*)d_in[7];
    float* out                = (float*)d_out;

    const int B     = in_sizes[1];
    const int T     = in_sizes[5];
    const int D     = in_sizes[3] / T;
    const int NPOS  = in_sizes[6] / D;
    const int NTIME = in_sizes[7] / D - 1;
    const float alpha = sqrtf((float)D);

    int2* meta = (int2*)d_ws;

    // Kernel A: per-token metadata
    {
        const int block = 256;
        const int grid  = (T + block - 1) / block;
        hstu_meta_kernel<<<grid, block, 0, stream>>>(
            seq_lengths, seq_offsets, num_targets, seq_timestamps,
            meta, T, B, NPOS, NTIME);
    }

    // Kernel B: fused gather + scale + add
    const int c4 = D / 4;
    const int block = 256;
    const int wpb = block / 64;
    const int RPW = 8;   // contiguous rows per wave

    if (c4 == 128 || c4 == 64 || c4 == 256) {
        int grid = (T + wpb * RPW - 1) / (wpb * RPW);
        grid = ((grid + 7) / 8) * 8;   // pad to multiple of 8 for bijective swizzle
        if (c4 == 128) {
            hstu_fuse_rows<7, 8><<<grid, block, 0, stream>>>(
                (const f32x4*)seq_emb, (const f32x4*)pos_emb, (const f32x4*)ts_emb,
                meta, (f32x4*)out, T, alpha);
        } else if (c4 == 64) {
            hstu_fuse_rows<6, 8><<<grid, block, 0, stream>>>(
                (const f32x4*)seq_emb, (const f32x4*)pos_emb, (const f32x4*)ts_emb,
                meta, (f32x4*)out, T, alpha);
        } else {
            hstu_fuse_rows<8, 8><<<grid, block, 0, stream>>>(
                (const f32x4*)seq_emb, (const f32x4*)pos_emb, (const f32x4*)ts_emb,
                meta, (f32x4*)out, T, alpha);
        }
    } else {
        const long total4l = (long)T * c4;
        const int total4 = (int)total4l;
        int grid = (int)((total4l + block - 1) / block);
        if (grid > 2048) grid = 2048;
        hstu_fuse_kernel_gen<<<grid, block, 0, stream>>>(
            (const f32x4*)seq_emb, (const f32x4*)pos_emb, (const f32x4*)ts_emb,
            meta, (f32x4*)out, total4, c4, alpha);
    }
}